// Round 6
// baseline (3341.079 us; speedup 1.0000x reference)
//
#include <hip/hip_runtime.h>

#define NUM_BINS 1025
#define NBLK 2048
#define BLOCK 256
#define SCALEF 1024.0f
#define INV_SCALE 0.0009765625f   // 2^-10

// One-kernel design:
//   +origin update -> LDS i32 histogram (DS pipe, ~1 lane/cy/CU)
//   -pre    update -> global i32 atomicAdd into 4KB bins_acc (VMEM/TCC pipe)
// The two atomic streams drain through independent pipes concurrently.
// Last-finishing block folds the |.|-sum reduction (completion counter).
__global__ __launch_bounds__(BLOCK) void hist_kernel(
    const float* __restrict__ od, const int* __restrict__ om,
    const float* __restrict__ pd, const int* __restrict__ nm,
    int* __restrict__ bins_acc, int* __restrict__ counter,
    float* __restrict__ out, int n)
{
    __shared__ int lh[NUM_BINS];
    const int tid = threadIdx.x;
    for (int b = tid; b < NUM_BINS; b += BLOCK) lh[b] = 0;
    __syncthreads();

    const int n4 = n >> 2;
    const float4* od4 = (const float4*)od;
    const int4*   om4 = (const int4*)om;
    const float4* pd4 = (const float4*)pd;
    const int4*   nm4 = (const int4*)nm;

    const int stride = gridDim.x * BLOCK;
    int i = blockIdx.x * BLOCK + tid;
    if (i < n4) {
        float4 d = od4[i]; int4 m = om4[i];
        float4 e = pd4[i]; int4 q = nm4[i];
        for (;;) {
            const int j = i + stride;
            const bool more = j < n4;
            float4 d2, e2; int4 m2, q2;
            if (more) { d2 = od4[j]; m2 = om4[j]; e2 = pd4[j]; q2 = nm4[j]; }
            // DS pipe: +origin
            atomicAdd(&lh[m.x],  __float2int_rn(d.x * SCALEF));
            atomicAdd(&lh[m.y],  __float2int_rn(d.y * SCALEF));
            atomicAdd(&lh[m.z],  __float2int_rn(d.z * SCALEF));
            atomicAdd(&lh[m.w],  __float2int_rn(d.w * SCALEF));
            // VMEM/TCC pipe: -pre (cache-resident, fire-and-forget)
            atomicAdd(&bins_acc[q.x], -__float2int_rn(e.x * SCALEF));
            atomicAdd(&bins_acc[q.y], -__float2int_rn(e.y * SCALEF));
            atomicAdd(&bins_acc[q.z], -__float2int_rn(e.z * SCALEF));
            atomicAdd(&bins_acc[q.w], -__float2int_rn(e.w * SCALEF));
            if (!more) break;
            d = d2; m = m2; e = e2; q = q2; i = j;
        }
    }
    // scalar tail (n % 4) — empty for 4096x4096; all-global for simplicity
    if (blockIdx.x == 0 && tid == 0) {
        for (int k = n4 << 2; k < n; ++k) {
            atomicAdd(&bins_acc[om[k]],  __float2int_rn(od[k] * SCALEF));
            atomicAdd(&bins_acc[nm[k]], -__float2int_rn(pd[k] * SCALEF));
        }
    }
    __syncthreads();

    // flush LDS histogram into the global accumulator
    for (int b = tid; b < NUM_BINS; b += BLOCK) {
        const int v = lh[b];
        if (v != 0) atomicAdd(&bins_acc[b], v);
    }

    // completion counter: last block computes the final loss
    __threadfence();
    __shared__ int lastFlag;
    if (tid == 0)
        lastFlag = (atomicAdd(counter, 1) == (int)gridDim.x - 1) ? 1 : 0;
    __syncthreads();
    if (lastFlag) {
        __threadfence();
        float v = 0.0f;
        for (int b = tid; b < NUM_BINS; b += BLOCK) {
            const int t = __hip_atomic_load(&bins_acc[b], __ATOMIC_RELAXED,
                                            __HIP_MEMORY_SCOPE_AGENT);
            v += fabsf((float)t);
        }
        for (int off = 32; off > 0; off >>= 1)
            v += __shfl_down(v, off, 64);
        __shared__ float wsum[4];
        if ((tid & 63) == 0) wsum[tid >> 6] = v;
        __syncthreads();
        if (tid == 0)
            out[0] = (wsum[0] + wsum[1] + wsum[2] + wsum[3]) * INV_SCALE;
    }
}

extern "C" void kernel_launch(void* const* d_in, const int* in_sizes, int n_in,
                              void* d_out, int out_size, void* d_ws, size_t ws_size,
                              hipStream_t stream) {
    const float* od = (const float*)d_in[0];   // origin_density
    const int*   om = (const int*)d_in[1];     // origin_mask
    const float* pd = (const float*)d_in[2];   // pre_density
    const int*   nm = (const int*)d_in[3];     // new_mask
    float* out    = (float*)d_out;
    int* bins_acc = (int*)d_ws;                // NUM_BINS ints
    int* counter  = bins_acc + NUM_BINS;       // +1 int
    const int n = in_sizes[0];

    hipMemsetAsync(d_ws, 0, (NUM_BINS + 1) * sizeof(int), stream);
    hist_kernel<<<NBLK, BLOCK, 0, stream>>>(od, om, pd, nm,
                                            bins_acc, counter, out, n);
}

// Round 7
// 293.187 us; speedup vs baseline: 11.3957x; 11.3957x over previous
//
#include <hip/hip_runtime.h>

#define NUM_BINS 1025
#define NBLK 2048
#define BLOCK 256
#define SCALEF 1024.0f
#define INV_SCALE 0.0009765625f   // 2^-10

// Single-kernel: per-block signed i32 LDS histogram (int DS atomics, the
// measured-fastest path), flushed via skip-zero global atomicAdd (r5-proven),
// last-finishing block computes the |.|-sum (completion counter, r6-proven).
__global__ __launch_bounds__(BLOCK) void hist_kernel(
    const float* __restrict__ od, const int* __restrict__ om,
    const float* __restrict__ pd, const int* __restrict__ nm,
    int* __restrict__ bins_acc, int* __restrict__ counter,
    float* __restrict__ out, int n)
{
    __shared__ int lh[NUM_BINS];
    const int tid = threadIdx.x;
    for (int b = tid; b < NUM_BINS; b += BLOCK) lh[b] = 0;
    __syncthreads();

    const int n4 = n >> 2;
    const float4* od4 = (const float4*)od;
    const int4*   om4 = (const int4*)om;
    const float4* pd4 = (const float4*)pd;
    const int4*   nm4 = (const int4*)nm;

    const int stride = gridDim.x * BLOCK;
    int i = blockIdx.x * BLOCK + tid;
    if (i < n4) {
        float4 d = od4[i]; int4 m = om4[i];
        float4 e = pd4[i]; int4 q = nm4[i];
        for (;;) {
            const int j = i + stride;
            const bool more = j < n4;
            float4 d2, e2; int4 m2, q2;
            if (more) { d2 = od4[j]; m2 = om4[j]; e2 = pd4[j]; q2 = nm4[j]; }
            atomicAdd(&lh[m.x],  __float2int_rn(d.x * SCALEF));
            atomicAdd(&lh[m.y],  __float2int_rn(d.y * SCALEF));
            atomicAdd(&lh[m.z],  __float2int_rn(d.z * SCALEF));
            atomicAdd(&lh[m.w],  __float2int_rn(d.w * SCALEF));
            atomicAdd(&lh[q.x], -__float2int_rn(e.x * SCALEF));
            atomicAdd(&lh[q.y], -__float2int_rn(e.y * SCALEF));
            atomicAdd(&lh[q.z], -__float2int_rn(e.z * SCALEF));
            atomicAdd(&lh[q.w], -__float2int_rn(e.w * SCALEF));
            if (!more) break;
            d = d2; m = m2; e = e2; q = q2; i = j;
        }
    }
    // scalar tail (n % 4) — empty for 4096x4096
    if (blockIdx.x == 0 && tid == 0) {
        for (int k = n4 << 2; k < n; ++k) {
            atomicAdd(&lh[om[k]],  __float2int_rn(od[k] * SCALEF));
            atomicAdd(&lh[nm[k]], -__float2int_rn(pd[k] * SCALEF));
        }
    }
    __syncthreads();

    // flush: skip-zero global atomicAdd per bin (spread-in-time, r5-proven OK)
    for (int b = tid; b < NUM_BINS; b += BLOCK) {
        const int v = lh[b];
        if (v != 0) atomicAdd(&bins_acc[b], v);
    }

    // completion counter: last block computes the final loss
    __threadfence();
    __shared__ int lastFlag;
    if (tid == 0)
        lastFlag = (atomicAdd(counter, 1) == (int)gridDim.x - 1) ? 1 : 0;
    __syncthreads();
    if (lastFlag) {
        __threadfence();
        float v = 0.0f;
        for (int b = tid; b < NUM_BINS; b += BLOCK) {
            const int t = __hip_atomic_load(&bins_acc[b], __ATOMIC_RELAXED,
                                            __HIP_MEMORY_SCOPE_AGENT);
            v += fabsf((float)t);
        }
        for (int off = 32; off > 0; off >>= 1)
            v += __shfl_down(v, off, 64);
        __shared__ float wsum[4];
        if ((tid & 63) == 0) wsum[tid >> 6] = v;
        __syncthreads();
        if (tid == 0)
            out[0] = (wsum[0] + wsum[1] + wsum[2] + wsum[3]) * INV_SCALE;
    }
}

extern "C" void kernel_launch(void* const* d_in, const int* in_sizes, int n_in,
                              void* d_out, int out_size, void* d_ws, size_t ws_size,
                              hipStream_t stream) {
    const float* od = (const float*)d_in[0];   // origin_density
    const int*   om = (const int*)d_in[1];     // origin_mask
    const float* pd = (const float*)d_in[2];   // pre_density
    const int*   nm = (const int*)d_in[3];     // new_mask
    float* out    = (float*)d_out;
    int* bins_acc = (int*)d_ws;                // NUM_BINS ints
    int* counter  = bins_acc + NUM_BINS;       // +1 int
    const int n = in_sizes[0];

    hipMemsetAsync(d_ws, 0, (NUM_BINS + 1) * sizeof(int), stream);
    hist_kernel<<<NBLK, BLOCK, 0, stream>>>(od, om, pd, nm,
                                            bins_acc, counter, out, n);
}

// Round 8
// 60.401 us; speedup vs baseline: 55.3152x; 4.8540x over previous
//
#include <hip/hip_runtime.h>

#define NUM_BINS 1025
#define NBLK 512
#define BLOCK 256
#define SCALEF 1024.0f
#define INV_SCALE 0.0009765625f   // 2^-10

// Single-kernel, FENCE-FREE completion:
//  - per-block signed i32 LDS histogram (int DS atomics — measured-fastest)
//  - flush via RETURNING device atomicAdd; consuming the old value forces
//    s_waitcnt vmcnt => the add has executed at the coherence point before
//    this block increments the completion counter (no __threadfence).
//  - last block re-reads bins with agent-scope atomic loads (L1-bypass).
__global__ __launch_bounds__(BLOCK) void hist_kernel(
    const float* __restrict__ od, const int* __restrict__ om,
    const float* __restrict__ pd, const int* __restrict__ nm,
    int* __restrict__ bins_acc, int* __restrict__ counter,
    float* __restrict__ out, int n)
{
    __shared__ int lh[NUM_BINS];
    const int tid = threadIdx.x;
    for (int b = tid; b < NUM_BINS; b += BLOCK) lh[b] = 0;
    __syncthreads();

    const int n4 = n >> 2;
    const float4* od4 = (const float4*)od;
    const int4*   om4 = (const int4*)om;
    const float4* pd4 = (const float4*)pd;
    const int4*   nm4 = (const int4*)nm;

    const int stride = gridDim.x * BLOCK;
    int i = blockIdx.x * BLOCK + tid;
    if (i < n4) {
        float4 d = od4[i]; int4 m = om4[i];
        float4 e = pd4[i]; int4 q = nm4[i];
        for (;;) {
            const int j = i + stride;
            const bool more = j < n4;
            float4 d2, e2; int4 m2, q2;
            if (more) { d2 = od4[j]; m2 = om4[j]; e2 = pd4[j]; q2 = nm4[j]; }
            atomicAdd(&lh[m.x],  __float2int_rn(d.x * SCALEF));
            atomicAdd(&lh[m.y],  __float2int_rn(d.y * SCALEF));
            atomicAdd(&lh[m.z],  __float2int_rn(d.z * SCALEF));
            atomicAdd(&lh[m.w],  __float2int_rn(d.w * SCALEF));
            atomicAdd(&lh[q.x], -__float2int_rn(e.x * SCALEF));
            atomicAdd(&lh[q.y], -__float2int_rn(e.y * SCALEF));
            atomicAdd(&lh[q.z], -__float2int_rn(e.z * SCALEF));
            atomicAdd(&lh[q.w], -__float2int_rn(e.w * SCALEF));
            if (!more) break;
            d = d2; m = m2; e = e2; q = q2; i = j;
        }
    }
    // scalar tail (n % 4) — empty for 4096x4096
    if (blockIdx.x == 0 && tid == 0) {
        for (int k = n4 << 2; k < n; ++k) {
            atomicAdd(&lh[om[k]],  __float2int_rn(od[k] * SCALEF));
            atomicAdd(&lh[nm[k]], -__float2int_rn(pd[k] * SCALEF));
        }
    }
    __syncthreads();

    // flush: RETURNING atomics; sink the old values so the wave waits for
    // completion at the coherence point (no fence needed).
    int sink = 0;
    for (int b = tid; b < NUM_BINS; b += BLOCK) {
        const int v = lh[b];
        if (v != 0)
            sink ^= __hip_atomic_fetch_add(&bins_acc[b], v,
                                           __ATOMIC_RELAXED,
                                           __HIP_MEMORY_SCOPE_AGENT);
    }
    asm volatile("" :: "v"(sink));   // keep live -> forces s_waitcnt vmcnt

    // completion counter (returning atomic, agent scope)
    __shared__ int lastFlag;
    if (tid == 0)
        lastFlag = (__hip_atomic_fetch_add(counter, 1, __ATOMIC_RELAXED,
                                           __HIP_MEMORY_SCOPE_AGENT)
                    == (int)gridDim.x - 1) ? 1 : 0;
    __syncthreads();
    if (lastFlag) {
        float v = 0.0f;
        for (int b = tid; b < NUM_BINS; b += BLOCK) {
            const int t = __hip_atomic_load(&bins_acc[b], __ATOMIC_RELAXED,
                                            __HIP_MEMORY_SCOPE_AGENT);
            v += fabsf((float)t);
        }
        for (int off = 32; off > 0; off >>= 1)
            v += __shfl_down(v, off, 64);
        __shared__ float wsum[4];
        if ((tid & 63) == 0) wsum[tid >> 6] = v;
        __syncthreads();
        if (tid == 0)
            out[0] = (wsum[0] + wsum[1] + wsum[2] + wsum[3]) * INV_SCALE;
    }
}

extern "C" void kernel_launch(void* const* d_in, const int* in_sizes, int n_in,
                              void* d_out, int out_size, void* d_ws, size_t ws_size,
                              hipStream_t stream) {
    const float* od = (const float*)d_in[0];   // origin_density
    const int*   om = (const int*)d_in[1];     // origin_mask
    const float* pd = (const float*)d_in[2];   // pre_density
    const int*   nm = (const int*)d_in[3];     // new_mask
    float* out    = (float*)d_out;
    int* bins_acc = (int*)d_ws;                // NUM_BINS ints
    int* counter  = bins_acc + NUM_BINS;       // +1 int
    const int n = in_sizes[0];

    hipMemsetAsync(d_ws, 0, (NUM_BINS + 1) * sizeof(int), stream);
    hist_kernel<<<NBLK, BLOCK, 0, stream>>>(od, om, pd, nm,
                                            bins_acc, counter, out, n);
}